// Round 8
// baseline (143.286 us; speedup 1.0000x reference)
//
#include <hip/hip_runtime.h>

// MultiScaleSampler R8: 4-layer MLP on MFMA (f16 in, f32 acc), transposed
// orientation D[out][pt], wave-private LDS, no barriers (R7 structure).
// vs R7: 4 pts/lane (256 pts/wave, 16 tiles) with 128-thread blocks —
// weight-frag setup amortized 2x, 16 independent tile chains per wave,
// LDS still 32KB/block (5 blocks/CU). VALU diet: med3 clamp + cvt_pkrtz
// (12->6 VALU per D-frag); layer-1 B-frags are exec-masked loads (lq==0)
// + zero registers, removing the k>=8 zero-fill writes entirely.

#define W_IMG 2048
#define NF    32
#define TILES 16     // per wave: 256 pts = 16 tiles x 16 pts

typedef __attribute__((ext_vector_type(8))) _Float16 f16x8;
typedef __attribute__((ext_vector_type(4))) _Float16 f16x4;
typedef __attribute__((ext_vector_type(2))) __fp16   h16x2;
typedef __attribute__((ext_vector_type(4))) float    f32x4;

union PkU { f16x4 v; h16x2 h[2]; };

__global__ __launch_bounds__(256) void fill_zero(float* __restrict__ out, int n) {
    int n4 = n >> 2;
    float4* o4 = (float4*)out;
    int stride = gridDim.x * blockDim.x;
    for (int i = blockIdx.x * blockDim.x + threadIdx.x; i < n4; i += stride)
        o4[i] = make_float4(0.f, 0.f, 0.f, 0.f);
    int t = (n4 << 2) + (blockIdx.x * blockDim.x + threadIdx.x);
    if (t < n) out[t] = 0.f;
}

__global__ __launch_bounds__(128) void msampler_mlp(
    const float* __restrict__ grid,   // (2, N)
    const int*   __restrict__ yi,     // (N,)
    const float* __restrict__ m,      // (3,3)
    const float* __restrict__ W1, const float* __restrict__ b1,   // (5,32),(32)
    const float* __restrict__ W2, const float* __restrict__ b2,   // (32,32),(32)
    const float* __restrict__ W3, const float* __restrict__ b3,   // (32,32),(32)
    const float* __restrict__ W4, const float* __restrict__ b4,   // (32,3),(3)
    float* __restrict__ out, int N)
{
    const int tid  = threadIdx.x;
    const int lane = tid & 63;
    const int wave = tid >> 6;        // 0..1
    const int lm   = lane & 15;
    const int lq   = lane >> 4;

    __shared__ __align__(16) char smem[2 * TILES * 1024];   // 32 KB
    char* buf = smem + wave * (TILES * 1024);

    // ---- one-time weight fragments (A = W^T: A[m=out][k=in]) ----
    f16x8 a1[2], a2[2], a3[2], a4;
    f32x4 cb1[2], cb2[2], cb3[2], cb4;
#pragma unroll
    for (int mh = 0; mh < 2; ++mh) {
        int outc = 16 * mh + lm;
#pragma unroll
        for (int j = 0; j < 8; ++j) {
            int k = lq * 8 + j;
            a1[mh][j] = (k < 5) ? (_Float16)W1[k * NF + outc] : (_Float16)0.0f;
            a2[mh][j] = (_Float16)W2[k * NF + outc];
            a3[mh][j] = (_Float16)W3[k * NF + outc];
        }
#pragma unroll
        for (int r = 0; r < 4; ++r) {
            int o = 16 * mh + lq * 4 + r;
            cb1[mh][r] = b1[o];
            cb2[mh][r] = b2[o];
            cb3[mh][r] = b3[o];
        }
    }
#pragma unroll
    for (int j = 0; j < 8; ++j) {
        int k = lq * 8 + j;
        a4[j] = (lm < 3) ? (_Float16)W4[k * 3 + lm] : (_Float16)0.0f;
    }
#pragma unroll
    for (int r = 0; r < 4; ++r) {
        int o = lq * 4 + r;
        cb4[r] = (o < 3) ? b4[o] : 0.f;
    }

    // ---- uniform homography scalars ----
    float m00=m[0], m01=m[1], m02=m[2];
    float m10=m[3], m11=m[4], m12=m[5];
    float m20=m[6], m21=m[7], m22=m[8];
    float det = m00*(m11*m22 - m12*m21)
              - m01*(m10*m22 - m12*m20)
              + m02*(m10*m21 - m11*m20);
    float adet = fabsf(det);

    // ---- features for 4 points (pt s = t*64 + lane) -> B-frag slots ----
    const int i0 = blockIdx.x * 512 + wave * 256;
    int ya[4];
#pragma unroll
    for (int t = 0; t < 4; ++t) {
        int i  = i0 + t * 64 + lane;
        int ic = i < N ? i : N - 1;
        float gx = grid[ic];
        float gy = grid[N + ic];
        int   y  = yi[ic];
        ya[t] = y;
        int py = y >> 11;            // / 2048
        int px = y & (W_IMG - 1);    // % 2048
        float denom = m20*(float)px + m21*(float)py + m22;
        float ad    = fabsf(denom);
        float dsda  = fminf(adet / (ad*ad*ad), 60000.f);  // f16-range clamp
        float fx = gx - floorf(gx);
        float fy = gy - floorf(gy);
        f16x8 f;
        f[0] = (_Float16)fx;         f[1] = (_Float16)fy;
        f[2] = (_Float16)(1.f-fx);   f[3] = (_Float16)(1.f-fy);
        f[4] = (_Float16)dsda;       f[5] = (_Float16)0.0f;
        f[6] = (_Float16)0.0f;       f[7] = (_Float16)0.0f;
        int g = t * 4 + lq;          // tile of this point
        *(f16x8*)(buf + g * 1024 + lm * 16) = f;   // k=0..7 slot of pt lm
    }

    // D-frag write offset within tile (mh handled separately)
    const int woff = (lq >> 1) * 256 + lm * 16 + (lq & 1) * 8;

    // ---- layer 1: B-frags are masked loads (lq==0 holds k=0..7 feats,
    //      other k-quads are ZERO registers -> junk-free, no zero-fill) ----
    {
        f16x8 bf[TILES];
#pragma unroll
        for (int g = 0; g < TILES; ++g) {
            f16x8 z = {};
            if (lq == 0) z = *(const f16x8*)(buf + g * 1024 + lm * 16);
            bf[g] = z;
        }
#pragma unroll
        for (int g = 0; g < TILES; ++g) {
#pragma unroll
            for (int mh = 0; mh < 2; ++mh) {
                f32x4 d = __builtin_amdgcn_mfma_f32_16x16x32_f16(
                    a1[mh], bf[g], cb1[mh], 0, 0, 0);
                PkU u;
                u.h[0] = __builtin_amdgcn_cvt_pkrtz(
                    fminf(fmaxf(d[0], 0.f), 60000.f),
                    fminf(fmaxf(d[1], 0.f), 60000.f));
                u.h[1] = __builtin_amdgcn_cvt_pkrtz(
                    fminf(fmaxf(d[2], 0.f), 60000.f),
                    fminf(fmaxf(d[3], 0.f), 60000.f));
                *(f16x4*)(buf + g * 1024 + mh * 512 + woff) = u.v;
            }
        }
    }

    // ---- layers 2,3: full B-frag reads ----
#define LAYER(AF, CB)                                                          \
    {                                                                          \
        f16x8 bf[TILES];                                                       \
        _Pragma("unroll")                                                      \
        for (int g = 0; g < TILES; ++g)                                        \
            bf[g] = *(const f16x8*)(buf + g * 1024 + lane * 16);               \
        _Pragma("unroll")                                                      \
        for (int g = 0; g < TILES; ++g) {                                      \
            _Pragma("unroll")                                                  \
            for (int mh = 0; mh < 2; ++mh) {                                   \
                f32x4 d = __builtin_amdgcn_mfma_f32_16x16x32_f16(              \
                    AF[mh], bf[g], CB[mh], 0, 0, 0);                           \
                PkU u;                                                         \
                u.h[0] = __builtin_amdgcn_cvt_pkrtz(                           \
                    fminf(fmaxf(d[0], 0.f), 60000.f),                          \
                    fminf(fmaxf(d[1], 0.f), 60000.f));                         \
                u.h[1] = __builtin_amdgcn_cvt_pkrtz(                           \
                    fminf(fmaxf(d[2], 0.f), 60000.f),                          \
                    fminf(fmaxf(d[3], 0.f), 60000.f));                         \
                *(f16x4*)(buf + g * 1024 + mh * 512 + woff) = u.v;             \
            }                                                                  \
        }                                                                      \
    }

    LAYER(a2, cb2)
    LAYER(a3, cb3)
#undef LAYER

    // ---- layer 4: 1 MFMA/tile; logits (rows 0..2) land in lq==0 lanes;
    //      stash f32x4 into own tile's first 256B (tile already consumed) ----
    {
        f16x8 bf[TILES];
#pragma unroll
        for (int g = 0; g < TILES; ++g)
            bf[g] = *(const f16x8*)(buf + g * 1024 + lane * 16);
#pragma unroll
        for (int g = 0; g < TILES; ++g) {
            f32x4 d = __builtin_amdgcn_mfma_f32_16x16x32_f16(a4, bf[g], cb4, 0, 0, 0);
            if (lq == 0)
                *(f32x4*)(buf + g * 1024 + lm * 16) = d;   // pt (16g+lm) logits
        }
    }

    // ---- softmax + scatter for own 4 points ----
#pragma unroll
    for (int t = 0; t < 4; ++t) {
        int g = t * 4 + lq;                       // tile of pt s = t*64+lane
        f32x4 L = *(const f32x4*)(buf + g * 1024 + lm * 16);
        float l0 = L[0], l1 = L[1], l2 = L[2];
        float mx = fmaxf(l0, fmaxf(l1, l2));
        float e0 = __expf(l0 - mx), e1 = __expf(l1 - mx), e2 = __expf(l2 - mx);
        float inv = 1.f / (e0 + e1 + e2);
        int i = i0 + t * 64 + lane;
        if (i < N) {
            int o = ya[t] * 3;
            out[o + 0] = e0 * inv;
            out[o + 1] = e1 * inv;
            out[o + 2] = e2 * inv;
        }
    }
}

extern "C" void kernel_launch(void* const* d_in, const int* in_sizes, int n_in,
                              void* d_out, int out_size, void* d_ws, size_t ws_size,
                              hipStream_t stream) {
    const float* grid = (const float*)d_in[0];
    const int*   yi   = (const int*)  d_in[1];
    const float* m    = (const float*)d_in[2];
    const float* W1   = (const float*)d_in[3];
    const float* b1   = (const float*)d_in[4];
    const float* W2   = (const float*)d_in[5];
    const float* b2   = (const float*)d_in[6];
    const float* W3   = (const float*)d_in[7];
    const float* b3   = (const float*)d_in[8];
    const float* W4   = (const float*)d_in[9];
    const float* b4   = (const float*)d_in[10];
    float* out = (float*)d_out;

    int N = in_sizes[1];  // yi element count

    fill_zero<<<2048, 256, 0, stream>>>(out, out_size);

    int grid_sz = (N + 511) / 512;   // 512 points per block (2 waves x 256)
    msampler_mlp<<<grid_sz, 128, 0, stream>>>(
        grid, yi, m, W1, b1, W2, b2, W3, b3, W4, b4, out, N);
}

// Round 9
// 136.892 us; speedup vs baseline: 1.0467x; 1.0467x over previous
//
#include <hip/hip_runtime.h>

// MultiScaleSampler R9: ZERO-LDS MLP. All 4 layers as 32x32x16 f16 MFMAs in
// transposed orientation D[out][pt]. Key insight: with the 32x32 C/D layout
// (col=lane&31, row=(reg&3)+8*(reg>>2)+4*(lane>>5)), the D->B-fragment
// transform between layers is exactly a lane<->lane^32 exchange =
// v_permlane32_swap_b32 (VALU pipe, gfx950). This removes ALL LDS traffic
// (R7/R8 spent ~18us serialized on the LDS pipe + occupancy was LDS-capped).
// Bias b1 rides in A1's k=5 slot (6th feature = 1.0); b2/b3 via MFMA C-init;
// b4 added as SGPR scalars in the epilogue. 2 pts/lane = 4 tiles/wave.

#define W_IMG 2048

typedef __attribute__((ext_vector_type(8)))  _Float16 f16x8;
typedef __attribute__((ext_vector_type(16))) float    f32x16;
typedef __attribute__((ext_vector_type(2)))  __fp16   h16x2;

union DWu { h16x2 h; unsigned u; };
union B8u { f16x8 v; unsigned u[4]; };

// Exchange: x'[32:63] = y[0:31], y'[0:31] = x[32:63] (halves swapped between
// the two registers). gfx950 v_permlane32_swap_b32 does this in one VALU op.
__device__ __forceinline__ void l32swap(unsigned &x, unsigned &y) {
#if __has_builtin(__builtin_amdgcn_permlane32_swap)
    auto r = __builtin_amdgcn_permlane32_swap(x, y, false, false);
    x = (unsigned)r[0];
    y = (unsigned)r[1];
#else
    unsigned sx = (unsigned)__shfl_xor((int)x, 32, 64);
    unsigned sy = (unsigned)__shfl_xor((int)y, 32, 64);
    bool up = (threadIdx.x & 32) != 0;
    unsigned nx = up ? sy : x;
    unsigned ny = up ? y  : sx;
    x = nx; y = ny;
#endif
}

__device__ __forceinline__ unsigned pkrc(float a, float b) {
    // relu + f16-range clamp + pack
    a = fminf(fmaxf(a, 0.f), 60000.f);
    b = fminf(fmaxf(b, 0.f), 60000.f);
    DWu d; d.h = __builtin_amdgcn_cvt_pkrtz(a, b);
    return d.u;
}

__global__ __launch_bounds__(256) void fill_zero(float* __restrict__ out, int n) {
    int n4 = n >> 2;
    float4* o4 = (float4*)out;
    int stride = gridDim.x * blockDim.x;
    for (int i = blockIdx.x * blockDim.x + threadIdx.x; i < n4; i += stride)
        o4[i] = make_float4(0.f, 0.f, 0.f, 0.f);
    int t = (n4 << 2) + (blockIdx.x * blockDim.x + threadIdx.x);
    if (t < n) out[t] = 0.f;
}

__global__ __launch_bounds__(256, 4) void msampler_mlp(
    const float* __restrict__ grid,   // (2, N)
    const int*   __restrict__ yi,     // (N,)
    const float* __restrict__ m,      // (3,3)
    const float* __restrict__ W1, const float* __restrict__ b1,   // (5,32),(32)
    const float* __restrict__ W2, const float* __restrict__ b2,   // (32,32),(32)
    const float* __restrict__ W3, const float* __restrict__ b3,   // (32,32),(32)
    const float* __restrict__ W4, const float* __restrict__ b4,   // (32,3),(3)
    float* __restrict__ out, int N)
{
    const int tid  = threadIdx.x;
    const int lane = tid & 63;
    const int wave = tid >> 6;
    const int m32  = lane & 31;   // MFMA row (A) / col (B,D) index
    const int h    = lane >> 5;   // k-half selector

    // ---- A fragments (A = W^T: A[m=out][k=in]); k = q*16 + 8h + j ----
    B8u a1;                       // layer 1, K=16: k=0..4 weights, k=5 bias
#pragma unroll
    for (int j = 0; j < 8; ++j) {
        int k = 8*h + j;
        float w = 0.f;
        if (h == 0) {
            if (k < 5)       w = W1[k*32 + m32];
            else if (k == 5) w = b1[m32];
        }
        a1.v[j] = (_Float16)w;
    }
    B8u a2[2], a3[2], a4[2];
#pragma unroll
    for (int q = 0; q < 2; ++q) {
#pragma unroll
        for (int j = 0; j < 8; ++j) {
            int k = q*16 + 8*h + j;
            a2[q].v[j] = (_Float16)W2[k*32 + m32];
            a3[q].v[j] = (_Float16)W3[k*32 + m32];
            a4[q].v[j] = (m32 < 3) ? (_Float16)W4[k*3 + m32] : (_Float16)0.f;
        }
    }
    // bias C-inits for layers 2,3 (row = (r&3) + 8*(r>>2) + 4h)
    f32x16 cb2, cb3;
#pragma unroll
    for (int r = 0; r < 16; ++r) {
        int row = (r & 3) + 8*(r >> 2) + 4*h;
        cb2[r] = b2[row];
        cb3[r] = b3[row];
    }
    const float B40 = b4[0], B41 = b4[1], B42 = b4[2];

    // ---- uniform homography scalars ----
    float m20 = m[6], m21 = m[7], m22 = m[8];
    float det = m[0]*(m[4]*m22 - m[5]*m21)
              - m[1]*(m[3]*m22 - m[5]*m20)
              + m[2]*(m[3]*m21 - m[4]*m20);
    float adet = fabsf(det);

    // ---- features for 2 points (pt = i0 + p*64 + lane), packed f16 ----
    const int i0 = blockIdx.x * 512 + wave * 128;
    int ya[2];
    unsigned fdw[2][3];
#pragma unroll
    for (int p = 0; p < 2; ++p) {
        int i  = i0 + p*64 + lane;
        int ic = i < N ? i : N - 1;
        float gx = grid[ic];
        float gy = grid[N + ic];
        int   y  = yi[ic];
        ya[p] = y;
        int py = y >> 11;            // / 2048
        int px = y & (W_IMG - 1);    // % 2048
        float denom = m20*(float)px + m21*(float)py + m22;
        float ad    = fabsf(denom);
        float dsda  = fminf(adet / (ad*ad*ad), 60000.f);
        float fx = gx - floorf(gx);
        float fy = gy - floorf(gy);
        DWu d0; d0.h = __builtin_amdgcn_cvt_pkrtz(fx, fy);
        DWu d1; d1.h = __builtin_amdgcn_cvt_pkrtz(1.f - fx, 1.f - fy);
        DWu d2; d2.h = __builtin_amdgcn_cvt_pkrtz(dsda, 1.f);   // 1.0 = bias slot
        fdw[p][0] = d0.u; fdw[p][1] = d1.u; fdw[p][2] = d2.u;
    }

    float lg[2][3];   // logits of owned pts
    unsigned dw[8];

#define PACKSWAP(ACC, BA, BB)                                                 \
    {                                                                         \
        _Pragma("unroll")                                                     \
        for (int r2 = 0; r2 < 8; ++r2)                                        \
            dw[r2] = pkrc(ACC[2*r2], ACC[2*r2+1]);                            \
        l32swap(dw[0], dw[2]); l32swap(dw[1], dw[3]);                         \
        l32swap(dw[4], dw[6]); l32swap(dw[5], dw[7]);                         \
        BA.u[0]=dw[0]; BA.u[1]=dw[1]; BA.u[2]=dw[2]; BA.u[3]=dw[3];           \
        BB.u[0]=dw[4]; BB.u[1]=dw[5]; BB.u[2]=dw[6]; BB.u[3]=dw[7];           \
    }

#pragma unroll
    for (int t = 0; t < 4; ++t) {
        const int  p     = t >> 1;
        const bool upper = (t & 1) != 0;   // tile covers pts of lanes 32..63

        // ---- layer-1 B fragment (K=16; h=1 lanes multiplied by A=0) ----
        B8u bf;
        if (!upper) {
            bf.u[0] = fdw[p][0]; bf.u[1] = fdw[p][1];
            bf.u[2] = fdw[p][2]; bf.u[3] = 0u;
        } else {
            unsigned x0 = fdw[p][0], y0 = 0u; l32swap(x0, y0);
            unsigned x1 = fdw[p][1], y1 = 0u; l32swap(x1, y1);
            unsigned x2 = fdw[p][2], y2 = 0u; l32swap(x2, y2);
            bf.u[0] = y0; bf.u[1] = y1; bf.u[2] = y2; bf.u[3] = 0u;
        }

        // ---- layer 1 (bias via k=5 slot, C=0) ----
        f32x16 acc;
#pragma unroll
        for (int r = 0; r < 16; ++r) acc[r] = 0.f;
        acc = __builtin_amdgcn_mfma_f32_32x32x16_f16(a1.v, bf.v, acc, 0, 0, 0);

        B8u bA, bB;
        PACKSWAP(acc, bA, bB)

        // ---- layer 2 (C = bias) ----
        acc = __builtin_amdgcn_mfma_f32_32x32x16_f16(a2[0].v, bA.v, cb2, 0, 0, 0);
        acc = __builtin_amdgcn_mfma_f32_32x32x16_f16(a2[1].v, bB.v, acc, 0, 0, 0);
        PACKSWAP(acc, bA, bB)

        // ---- layer 3 ----
        acc = __builtin_amdgcn_mfma_f32_32x32x16_f16(a3[0].v, bA.v, cb3, 0, 0, 0);
        acc = __builtin_amdgcn_mfma_f32_32x32x16_f16(a3[1].v, bB.v, acc, 0, 0, 0);
        PACKSWAP(acc, bA, bB)

        // ---- layer 4 (C=0; logit rows 0..2 = regs 0..2 of h==0 lanes) ----
        f32x16 acc4;
#pragma unroll
        for (int r = 0; r < 16; ++r) acc4[r] = 0.f;
        acc4 = __builtin_amdgcn_mfma_f32_32x32x16_f16(a4[0].v, bA.v, acc4, 0, 0, 0);
        acc4 = __builtin_amdgcn_mfma_f32_32x32x16_f16(a4[1].v, bB.v, acc4, 0, 0, 0);

        if (!upper) {
            // pts owned by lanes 0..31; their logits already sit there
            lg[p][0] = acc4[0]; lg[p][1] = acc4[1]; lg[p][2] = acc4[2];
        } else {
            // hand logits up to lanes 32..63
            unsigned g0 = __float_as_uint(acc4[0]), d0 = 0u; l32swap(d0, g0);
            unsigned g1 = __float_as_uint(acc4[1]), d1 = 0u; l32swap(d1, g1);
            unsigned g2 = __float_as_uint(acc4[2]), d2 = 0u; l32swap(d2, g2);
            if (lane >= 32) {
                lg[p][0] = __uint_as_float(d0);
                lg[p][1] = __uint_as_float(d1);
                lg[p][2] = __uint_as_float(d2);
            }
        }
    }
#undef PACKSWAP

    // ---- softmax + scatter ----
#pragma unroll
    for (int p = 0; p < 2; ++p) {
        float l0 = lg[p][0] + B40;
        float l1 = lg[p][1] + B41;
        float l2 = lg[p][2] + B42;
        float mx = fmaxf(l0, fmaxf(l1, l2));
        float e0 = __expf(l0 - mx), e1 = __expf(l1 - mx), e2 = __expf(l2 - mx);
        float inv = 1.f / (e0 + e1 + e2);
        int i = i0 + p*64 + lane;
        if (i < N) {
            int o = ya[p] * 3;
            out[o + 0] = e0 * inv;
            out[o + 1] = e1 * inv;
            out[o + 2] = e2 * inv;
        }
    }
}

extern "C" void kernel_launch(void* const* d_in, const int* in_sizes, int n_in,
                              void* d_out, int out_size, void* d_ws, size_t ws_size,
                              hipStream_t stream) {
    const float* grid = (const float*)d_in[0];
    const int*   yi   = (const int*)  d_in[1];
    const float* m    = (const float*)d_in[2];
    const float* W1   = (const float*)d_in[3];
    const float* b1   = (const float*)d_in[4];
    const float* W2   = (const float*)d_in[5];
    const float* b2   = (const float*)d_in[6];
    const float* W3   = (const float*)d_in[7];
    const float* b3   = (const float*)d_in[8];
    const float* W4   = (const float*)d_in[9];
    const float* b4   = (const float*)d_in[10];
    float* out = (float*)d_out;

    int N = in_sizes[1];  // yi element count

    fill_zero<<<2048, 256, 0, stream>>>(out, out_size);

    int grid_sz = (N + 511) / 512;   // 512 pts/block (4 waves x 128)
    msampler_mlp<<<grid_sz, 256, 0, stream>>>(
        grid, yi, m, W1, b1, W2, b2, W3, b3, W4, b4, out, N);
}